// Round 3
// baseline (228.823 us; speedup 1.0000x reference)
//
#include <hip/hip_runtime.h>
#include <math.h>

// Problem constants (reference: B=4, N=8192, points are [B,N,3] fp32)
#define BATCH 4
#define NPTS 8192
#define BN (BATCH * NPTS)
#define NZB 16                    // 4 searches x 4 batches
#define QK 8                      // queries per lane in the scan
#define SPL 16                    // candidate splits
#define SLICE (NPTS / SPL)        // 512 candidates per scan block
#define QBLK (256 * QK)           // 2048 queries per scan block

// Workspace: [0] double acc | [64] int idx_all[NZB*NPTS] (512KB)
//            [64+512K] float part_d[SPL][NZB*NPTS] (8MB)

__device__ __forceinline__ void pick_ab(int z, const float* pw, const float* pp,
                                        const float* tw, const float* tp,
                                        const float** qa, const float** cb) {
  if (z == 0)      { *qa = pw; *cb = pp; }
  else if (z == 1) { *qa = pp; *cb = pw; }
  else if (z == 2) { *qa = tw; *cb = tp; }
  else             { *qa = tp; *cb = tw; }
}

// ---------------------------------------------------------------------------
// Pass 1: pure min-distance scan (no index bookkeeping).
// d(q,m) = ||b_m||^2 - 2 q.b_m  via 3 fma; min via v_min3 over candidate pairs.
// grid = (NPTS/QBLK=4, SPL=16, NZB=16) = 1024 blocks, block = 256.
// __launch_bounds__(256,4): cap 128 VGPRs so 4 waves/SIMD stay resident while
// leaving temp registers for 16 independent fma chains (ILP).
// ---------------------------------------------------------------------------
__global__ __launch_bounds__(256, 4) void nn_partial_kernel(
    const float* __restrict__ pw, const float* __restrict__ pp,
    const float* __restrict__ tw, const float* __restrict__ tp,
    float* __restrict__ part_d) {
  __shared__ float4 sh[SLICE];   // 8 KB

  const int zb = blockIdx.z;
  const int z = zb >> 2;
  const int b = zb & 3;
  const float* qa;
  const float* cb;
  pick_ab(z, pw, pp, tw, tp, &qa, &cb);

  const int tid = threadIdx.x;
  const int cslice = blockIdx.y * SLICE;
  const float* cbb = cb + (size_t)b * NPTS * 3;

  // Stage slice as (x,y,z,||b||^2); b2 formula must match nn_resolve exactly.
  for (int m = tid; m < SLICE; m += 256) {
    const float* c = cbb + (size_t)(cslice + m) * 3;
    const float bx = c[0], by = c[1], bz = c[2];
    sh[m] = make_float4(bx, by, bz, fmaf(bx, bx, fmaf(by, by, bz * bz)));
  }
  __syncthreads();

  const int qbase = blockIdx.x * QBLK;
  float qx[QK], qy[QK], qz[QK], dmin[QK];
  #pragma unroll
  for (int k = 0; k < QK; ++k) {
    const int n = qbase + tid + k * 256;
    const float* q = qa + ((size_t)b * NPTS + n) * 3;
    qx[k] = -2.0f * q[0];
    qy[k] = -2.0f * q[1];
    qz[k] = -2.0f * q[2];
    dmin[k] = INFINITY;
  }

  // 16 independent fma chains per pair-step; min3 merges 2 candidates/query.
  #pragma unroll 2
  for (int p = 0; p < SLICE / 2; ++p) {
    const float4 c0 = sh[2 * p];
    const float4 c1 = sh[2 * p + 1];
    float t0[QK], t1[QK];
    #pragma unroll
    for (int k = 0; k < QK; ++k)
      t0[k] = fmaf(qx[k], c0.x, fmaf(qy[k], c0.y, fmaf(qz[k], c0.z, c0.w)));
    #pragma unroll
    for (int k = 0; k < QK; ++k)
      t1[k] = fmaf(qx[k], c1.x, fmaf(qy[k], c1.y, fmaf(qz[k], c1.z, c1.w)));
    #pragma unroll
    for (int k = 0; k < QK; ++k)
      dmin[k] = fminf(fminf(t0[k], t1[k]), dmin[k]);   // -> v_min3_f32
  }

  // part_d[split][query]: coalesced stores across tid.
  #pragma unroll
  for (int k = 0; k < QK; ++k) {
    const int n = qbase + tid + k * 256;
    part_d[(size_t)blockIdx.y * (NZB * NPTS) + (size_t)zb * NPTS + n] = dmin[k];
  }
}

// ---------------------------------------------------------------------------
// Pass 2: one WAVE per query. Merge the 16 split minima (first-min: lowest
// split wins ties), then all 64 lanes rescan the winning 512-candidate slice
// (8 candidates/lane, contiguous loads, bit-identical fma chain) and
// int-min-reduce the first exact match.
// block = 1024 (16 waves), grid = NZB*NPTS/16 = 8192 blocks.
// ---------------------------------------------------------------------------
__global__ __launch_bounds__(1024) void nn_resolve_kernel(
    const float* __restrict__ pw, const float* __restrict__ pp,
    const float* __restrict__ tw, const float* __restrict__ tp,
    const float* __restrict__ part_d, int* __restrict__ idx_all,
    double* __restrict__ acc) {
  if (blockIdx.x == 0 && threadIdx.x == 0) *acc = 0.0;  // before loss dispatch

  const int qid = (blockIdx.x * 1024 + threadIdx.x) >> 6;  // [0, NZB*NPTS)
  const int lane = threadIdx.x & 63;
  const int zb = qid >> 13;
  const int n = qid & (NPTS - 1);
  const int z = zb >> 2;
  const int b = zb & 3;
  const float* qa;
  const float* cb;
  pick_ab(z, pw, pp, tw, tp, &qa, &cb);

  // Merge: lane s < SPL holds split s's minimum; reduce keeping lowest split.
  float d = INFINITY;
  int s = lane;
  if (lane < SPL) d = part_d[(size_t)lane * (NZB * NPTS) + qid];
  #pragma unroll
  for (int off = 8; off > 0; off >>= 1) {
    const float d2 = __shfl_down(d, off);
    const int s2 = __shfl_down(s, off);
    if (d2 < d || (d2 == d && s2 < s)) { d = d2; s = s2; }
  }
  const float best_d = __shfl(d, 0);
  const int best_s = __shfl(s, 0);

  const float* q = qa + ((size_t)b * NPTS + n) * 3;
  const float qx = -2.0f * q[0];
  const float qy = -2.0f * q[1];
  const float qz = -2.0f * q[2];
  const float* cbb = cb + (size_t)b * NPTS * 3;
  const int base = best_s * SLICE;

  int best_i = 0x7fffffff;
  #pragma unroll
  for (int j = 0; j < SLICE / 64; ++j) {       // 8 candidates per lane
    const int m = base + lane * (SLICE / 64) + j;
    const float* c = cbb + (size_t)m * 3;
    const float bx = c[0], by = c[1], bz = c[2];
    const float b2 = fmaf(bx, bx, fmaf(by, by, bz * bz));
    const float dd = fmaf(qx, bx, fmaf(qy, by, fmaf(qz, bz, b2)));
    if (dd == best_d) best_i = min(best_i, m);  // first (smallest) match
  }
  #pragma unroll
  for (int off = 32; off > 0; off >>= 1)
    best_i = min(best_i, __shfl_down(best_i, off));
  if (lane == 0) idx_all[qid] = best_i;
}

// ---------------------------------------------------------------------------
// Loss: 4 MSN terms split across blockIdx.y.
// loss = 0.25 * (sum of 4 squared-norm sums) / (B*N)
// ---------------------------------------------------------------------------
__device__ __forceinline__ float3 ld3(const float* __restrict__ p, int i) {
  const float* q = p + (size_t)i * 3;
  return make_float3(q[0], q[1], q[2]);
}

__device__ __forceinline__ float diff_nrm2(float3 a1, float3 a2, float3 b1, float3 b2) {
  const float x = (a1.x - a2.x) - (b1.x - b2.x);
  const float y = (a1.y - a2.y) - (b1.y - b2.y);
  const float z = (a1.z - a2.z) - (b1.z - b2.z);
  return fmaf(x, x, fmaf(y, y, z * z));
}

__global__ __launch_bounds__(256) void loss_kernel(
    const float* __restrict__ pw, const float* __restrict__ pp,
    const float* __restrict__ tw, const float* __restrict__ tp,
    const int* __restrict__ ipw, const int* __restrict__ itw,
    const int* __restrict__ ipp, const int* __restrict__ itp,
    const int* __restrict__ idx_all, double* __restrict__ acc) {
  const int gid = blockIdx.x * 256 + threadIdx.x;  // [0, B*N)
  const int term = blockIdx.y;
  const int b = gid >> 13;
  const int n = gid & (NPTS - 1);
  const int base = b * NPTS;

  const float* PW = pw + (size_t)base * 3;
  const float* PP = pp + (size_t)base * 3;
  const float* TW = tw + (size_t)base * 3;
  const float* TP = tp + (size_t)base * 3;
  const int* I1P = idx_all + (0 * BATCH + b) * NPTS;  // NN pial for white (pred)
  const int* I2P = idx_all + (1 * BATCH + b) * NPTS;  // NN white for pial (pred)
  const int* I1T = idx_all + (2 * BATCH + b) * NPTS;  // NN pial for white (true)
  const int* I2T = idx_all + (3 * BATCH + b) * NPTS;  // NN white for pial (true)

  float sv;
  if (term == 0) {        // msn(yp_inner, yt_inner[i_pred_white])
    const int j = ipw[base + n];
    sv = diff_nrm2(ld3(PP, I1P[n]), ld3(PW, n), ld3(TP, I1T[j]), ld3(TW, j));
  } else if (term == 1) { // msn(yp_inner[i_true_white], yt_inner)
    const int k = itw[base + n];
    sv = diff_nrm2(ld3(PP, I1P[k]), ld3(PW, k), ld3(TP, I1T[n]), ld3(TW, n));
  } else if (term == 2) { // msn(yp_outer, yt_outer[i_pred_pial])
    const int j = ipp[base + n];
    sv = diff_nrm2(ld3(PP, n), ld3(PW, I2P[n]), ld3(TP, j), ld3(TW, I2T[j]));
  } else {                // msn(yp_outer[i_true_pial], yt_outer)
    const int k = itp[base + n];
    sv = diff_nrm2(ld3(PP, k), ld3(PW, I2P[k]), ld3(TP, n), ld3(TW, I2T[n]));
  }

  double ds = (double)sv;
  #pragma unroll
  for (int o = 32; o > 0; o >>= 1) ds += __shfl_down(ds, o, 64);
  if ((threadIdx.x & 63) == 0) atomicAdd(acc, ds);
}

__global__ void finalize_kernel(const double* __restrict__ acc,
                                float* __restrict__ out) {
  out[0] = (float)(0.25 * (*acc) / (double)BN);
}

// ---------------------------------------------------------------------------
extern "C" void kernel_launch(void* const* d_in, const int* in_sizes, int n_in,
                              void* d_out, int out_size, void* d_ws, size_t ws_size,
                              hipStream_t stream) {
  const float* pw = (const float*)d_in[0];
  const float* pp = (const float*)d_in[1];
  const float* tw = (const float*)d_in[2];
  const float* tp = (const float*)d_in[3];
  const int* ipw = (const int*)d_in[4];
  const int* itw = (const int*)d_in[5];
  const int* ipp = (const int*)d_in[6];
  const int* itp = (const int*)d_in[7];

  char* ws = (char*)d_ws;
  double* acc = (double*)ws;                              // 8 B
  int* idx_all = (int*)(ws + 64);                         // 512 KB
  float* part_d = (float*)(ws + 64 + (size_t)NZB * NPTS * 4);  // 8 MB
  float* out = (float*)d_out;

  dim3 grid_nn(NPTS / QBLK, SPL, NZB);   // (4, 16, 16) = 1024 blocks
  nn_partial_kernel<<<grid_nn, 256, 0, stream>>>(pw, pp, tw, tp, part_d);

  nn_resolve_kernel<<<(NZB * NPTS) / 16, 1024, 0, stream>>>(
      pw, pp, tw, tp, part_d, idx_all, acc);

  dim3 grid_loss(BN / 256, 4);
  loss_kernel<<<grid_loss, 256, 0, stream>>>(pw, pp, tw, tp, ipw, itw, ipp, itp,
                                             idx_all, acc);

  finalize_kernel<<<1, 1, 0, stream>>>(acc, out);
}

// Round 4
// 212.434 us; speedup vs baseline: 1.0771x; 1.0771x over previous
//
#include <hip/hip_runtime.h>
#include <math.h>

// Problem constants (reference: B=4, N=8192, points are [B,N,3] fp32)
#define BATCH 4
#define NPTS 8192
#define BN (BATCH * NPTS)
#define NZB 16                 // 4 searches x 4 batches
#define QK 8                   // queries per lane in the scan
#define QBLK (256 * QK)        // 2048 queries per scan block
#define SUBT 64                // provenance subtile (resolve rescans this many)

// Workspace: [0] double acc | [64] int idx_all[NZB*NPTS] (512KB)
//            [64+512K] float part_d[SPL][NZB*NPTS]
//            [after]   u8    part_t[SPL][NZB*NPTS]   (global subtile id, <128)

__device__ __forceinline__ void pick_ab(int z, const float* pw, const float* pp,
                                        const float* tw, const float* tp,
                                        const float** qa, const float** cb) {
  if (z == 0)      { *qa = pw; *cb = pp; }
  else if (z == 1) { *qa = pp; *cb = pw; }
  else if (z == 2) { *qa = tw; *cb = tp; }
  else             { *qa = tp; *cb = tw; }
}

// ---------------------------------------------------------------------------
// Pass 1: min-distance scan + subtile provenance.
// d(q,m) = ||b_m||^2 - 2 q.b_m  (3 fma); min3 merges candidate pairs.
// Provenance: first subtile (64 cands) achieving a strict improvement —
// combined with ordered split merge this reproduces jnp.argmin first-min.
// grid = (4, SPL, NZB), block = 256.
// ---------------------------------------------------------------------------
template <int SPL>
__global__ __launch_bounds__(256, 4) void nn_partial_kernel(
    const float* __restrict__ pw, const float* __restrict__ pp,
    const float* __restrict__ tw, const float* __restrict__ tp,
    float* __restrict__ part_d, unsigned char* __restrict__ part_t) {
  constexpr int SLICE = NPTS / SPL;
  constexpr int NSUB = SLICE / SUBT;
  __shared__ float4 sh[SLICE];

  const int zb = blockIdx.z;
  const int z = zb >> 2;
  const int b = zb & 3;
  const float* qa;
  const float* cb;
  pick_ab(z, pw, pp, tw, tp, &qa, &cb);

  const int tid = threadIdx.x;
  const int cslice = blockIdx.y * SLICE;
  const float* cbb = cb + (size_t)b * NPTS * 3;

  // Stage slice as (x,y,z,||b||^2); b2 formula must match nn_resolve exactly.
  for (int m = tid; m < SLICE; m += 256) {
    const float* c = cbb + (size_t)(cslice + m) * 3;
    const float bx = c[0], by = c[1], bz = c[2];
    sh[m] = make_float4(bx, by, bz, fmaf(bx, bx, fmaf(by, by, bz * bz)));
  }
  __syncthreads();

  const int qbase = blockIdx.x * QBLK;
  float qx[QK], qy[QK], qz[QK], dmin[QK];
  int tile[QK];
  #pragma unroll
  for (int k = 0; k < QK; ++k) {
    const int n = qbase + tid + k * 256;
    const float* q = qa + ((size_t)b * NPTS + n) * 3;
    qx[k] = -2.0f * q[0];
    qy[k] = -2.0f * q[1];
    qz[k] = -2.0f * q[2];
    dmin[k] = INFINITY;
    tile[k] = 0;
  }

  for (int sub = 0; sub < NSUB; ++sub) {
    float pre[QK];
    #pragma unroll
    for (int k = 0; k < QK; ++k) pre[k] = dmin[k];

    const int cb0 = sub * SUBT;
    #pragma unroll 2
    for (int p = 0; p < SUBT / 2; ++p) {
      const float4 c0 = sh[cb0 + 2 * p];
      const float4 c1 = sh[cb0 + 2 * p + 1];
      float t0[QK], t1[QK];
      #pragma unroll
      for (int k = 0; k < QK; ++k)
        t0[k] = fmaf(qx[k], c0.x, fmaf(qy[k], c0.y, fmaf(qz[k], c0.z, c0.w)));
      #pragma unroll
      for (int k = 0; k < QK; ++k)
        t1[k] = fmaf(qx[k], c1.x, fmaf(qy[k], c1.y, fmaf(qz[k], c1.z, c1.w)));
      #pragma unroll
      for (int k = 0; k < QK; ++k)
        dmin[k] = fminf(fminf(t0[k], t1[k]), dmin[k]);   // v_min3_f32
    }
    const int g = blockIdx.y * NSUB + sub;   // global subtile id, [0,128)
    #pragma unroll
    for (int k = 0; k < QK; ++k)
      tile[k] = (dmin[k] < pre[k]) ? g : tile[k];  // strict <: first-min kept
  }

  #pragma unroll
  for (int k = 0; k < QK; ++k) {
    const int n = qbase + tid + k * 256;
    const size_t o = (size_t)blockIdx.y * (NZB * NPTS) + (size_t)zb * NPTS + n;
    part_d[o] = dmin[k];
    part_t[o] = (unsigned char)tile[k];
  }
}

// ---------------------------------------------------------------------------
// Pass 2: one wave per query. Lanes < SPL merge split minima (tie-break on
// global subtile id == candidate order == first-min), then the 64 lanes
// rescan the winning 64-candidate subtile (contiguous 768B, bit-identical
// fma chain) and int-min-reduce the first exact match.
// grid = NZB*NPTS/4 blocks, block = 256 (4 waves).
// ---------------------------------------------------------------------------
template <int SPL>
__global__ __launch_bounds__(256) void nn_resolve_kernel(
    const float* __restrict__ pw, const float* __restrict__ pp,
    const float* __restrict__ tw, const float* __restrict__ tp,
    const float* __restrict__ part_d, const unsigned char* __restrict__ part_t,
    int* __restrict__ idx_all, double* __restrict__ acc) {
  if (blockIdx.x == 0 && threadIdx.x == 0) *acc = 0.0;  // before loss dispatch

  const int qid = (blockIdx.x * 256 + threadIdx.x) >> 6;  // [0, NZB*NPTS)
  const int lane = threadIdx.x & 63;
  const int zb = qid >> 13;
  const int n = qid & (NPTS - 1);
  const int z = zb >> 2;
  const int b = zb & 3;
  const float* qa;
  const float* cb;
  pick_ab(z, pw, pp, tw, tp, &qa, &cb);

  // Merge: lane s < SPL holds split s's (min, subtile); keep lowest subtile
  // id on exact ties (subtile ids follow candidate order across splits).
  float d = INFINITY;
  int t = 0x7fffffff;
  if (lane < SPL) {
    const size_t o = (size_t)lane * (NZB * NPTS) + qid;
    d = part_d[o];
    t = part_t[o];
  }
  #pragma unroll
  for (int off = 16; off > 0; off >>= 1) {
    const float d2 = __shfl_down(d, off);
    const int t2 = __shfl_down(t, off);
    if (d2 < d || (d2 == d && t2 < t)) { d = d2; t = t2; }
  }
  const float best_d = __shfl(d, 0);
  const int best_g = __shfl(t, 0);

  const float* q = qa + ((size_t)b * NPTS + n) * 3;
  const float qx = -2.0f * q[0];
  const float qy = -2.0f * q[1];
  const float qz = -2.0f * q[2];
  const float* cbb = cb + (size_t)b * NPTS * 3;

  const int m = best_g * SUBT + lane;        // one candidate per lane
  const float* c = cbb + (size_t)m * 3;
  const float bx = c[0], by = c[1], bz = c[2];
  const float b2 = fmaf(bx, bx, fmaf(by, by, bz * bz));
  const float dd = fmaf(qx, bx, fmaf(qy, by, fmaf(qz, bz, b2)));
  int idx = (dd == best_d) ? m : 0x7fffffff;
  #pragma unroll
  for (int off = 32; off > 0; off >>= 1)
    idx = min(idx, __shfl_down(idx, off));
  if (lane == 0) idx_all[qid] = idx;
}

// ---------------------------------------------------------------------------
// Loss: 4 MSN terms split across blockIdx.y.
// loss = 0.25 * (sum of 4 squared-norm sums) / (B*N)
// ---------------------------------------------------------------------------
__device__ __forceinline__ float3 ld3(const float* __restrict__ p, int i) {
  const float* q = p + (size_t)i * 3;
  return make_float3(q[0], q[1], q[2]);
}

__device__ __forceinline__ float diff_nrm2(float3 a1, float3 a2, float3 b1, float3 b2) {
  const float x = (a1.x - a2.x) - (b1.x - b2.x);
  const float y = (a1.y - a2.y) - (b1.y - b2.y);
  const float z = (a1.z - a2.z) - (b1.z - b2.z);
  return fmaf(x, x, fmaf(y, y, z * z));
}

__global__ __launch_bounds__(256) void loss_kernel(
    const float* __restrict__ pw, const float* __restrict__ pp,
    const float* __restrict__ tw, const float* __restrict__ tp,
    const int* __restrict__ ipw, const int* __restrict__ itw,
    const int* __restrict__ ipp, const int* __restrict__ itp,
    const int* __restrict__ idx_all, double* __restrict__ acc) {
  const int gid = blockIdx.x * 256 + threadIdx.x;  // [0, B*N)
  const int term = blockIdx.y;
  const int b = gid >> 13;
  const int n = gid & (NPTS - 1);
  const int base = b * NPTS;

  const float* PW = pw + (size_t)base * 3;
  const float* PP = pp + (size_t)base * 3;
  const float* TW = tw + (size_t)base * 3;
  const float* TP = tp + (size_t)base * 3;
  const int* I1P = idx_all + (0 * BATCH + b) * NPTS;  // NN pial for white (pred)
  const int* I2P = idx_all + (1 * BATCH + b) * NPTS;  // NN white for pial (pred)
  const int* I1T = idx_all + (2 * BATCH + b) * NPTS;  // NN pial for white (true)
  const int* I2T = idx_all + (3 * BATCH + b) * NPTS;  // NN white for pial (true)

  float sv;
  if (term == 0) {        // msn(yp_inner, yt_inner[i_pred_white])
    const int j = ipw[base + n];
    sv = diff_nrm2(ld3(PP, I1P[n]), ld3(PW, n), ld3(TP, I1T[j]), ld3(TW, j));
  } else if (term == 1) { // msn(yp_inner[i_true_white], yt_inner)
    const int k = itw[base + n];
    sv = diff_nrm2(ld3(PP, I1P[k]), ld3(PW, k), ld3(TP, I1T[n]), ld3(TW, n));
  } else if (term == 2) { // msn(yp_outer, yt_outer[i_pred_pial])
    const int j = ipp[base + n];
    sv = diff_nrm2(ld3(PP, n), ld3(PW, I2P[n]), ld3(TP, j), ld3(TW, I2T[j]));
  } else {                // msn(yp_outer[i_true_pial], yt_outer)
    const int k = itp[base + n];
    sv = diff_nrm2(ld3(PP, k), ld3(PW, I2P[k]), ld3(TP, n), ld3(TW, I2T[n]));
  }

  double ds = (double)sv;
  #pragma unroll
  for (int o = 32; o > 0; o >>= 1) ds += __shfl_down(ds, o, 64);
  if ((threadIdx.x & 63) == 0) atomicAdd(acc, ds);
}

__global__ void finalize_kernel(const double* __restrict__ acc,
                                float* __restrict__ out) {
  out[0] = (float)(0.25 * (*acc) / (double)BN);
}

// ---------------------------------------------------------------------------
template <int SPL>
static void run_pipeline(const float* pw, const float* pp, const float* tw,
                         const float* tp, const int* ipw, const int* itw,
                         const int* ipp, const int* itp, char* ws, float* out,
                         hipStream_t stream) {
  double* acc = (double*)ws;
  int* idx_all = (int*)(ws + 64);
  float* part_d = (float*)(ws + 64 + (size_t)NZB * NPTS * 4);
  unsigned char* part_t =
      (unsigned char*)(ws + 64 + (size_t)NZB * NPTS * 4 +
                       (size_t)SPL * NZB * NPTS * 4);

  dim3 grid_nn(NPTS / QBLK, SPL, NZB);
  nn_partial_kernel<SPL><<<grid_nn, 256, 0, stream>>>(pw, pp, tw, tp, part_d,
                                                      part_t);
  nn_resolve_kernel<SPL><<<(NZB * NPTS) / 4, 256, 0, stream>>>(
      pw, pp, tw, tp, part_d, part_t, idx_all, acc);

  dim3 grid_loss(BN / 256, 4);
  loss_kernel<<<grid_loss, 256, 0, stream>>>(pw, pp, tw, tp, ipw, itw, ipp, itp,
                                             idx_all, acc);
  finalize_kernel<<<1, 1, 0, stream>>>(acc, out);
}

extern "C" void kernel_launch(void* const* d_in, const int* in_sizes, int n_in,
                              void* d_out, int out_size, void* d_ws, size_t ws_size,
                              hipStream_t stream) {
  const float* pw = (const float*)d_in[0];
  const float* pp = (const float*)d_in[1];
  const float* tw = (const float*)d_in[2];
  const float* tp = (const float*)d_in[3];
  const int* ipw = (const int*)d_in[4];
  const int* itw = (const int*)d_in[5];
  const int* ipp = (const int*)d_in[6];
  const int* itp = (const int*)d_in[7];
  char* ws = (char*)d_ws;
  float* out = (float*)d_out;

  // ws need per SPL: 64 + idx(512K) + part_d(SPL*512K) + part_t(SPL*128K)
  const size_t base_need = 64 + (size_t)NZB * NPTS * 4;
  const size_t per_spl = (size_t)NZB * NPTS * 5;
  if (ws_size >= base_need + 32 * per_spl) {
    run_pipeline<32>(pw, pp, tw, tp, ipw, itw, ipp, itp, ws, out, stream);
  } else if (ws_size >= base_need + 16 * per_spl) {
    run_pipeline<16>(pw, pp, tw, tp, ipw, itw, ipp, itp, ws, out, stream);
  } else {
    run_pipeline<8>(pw, pp, tw, tp, ipw, itw, ipp, itp, ws, out, stream);
  }
}

// Round 5
// 206.540 us; speedup vs baseline: 1.1079x; 1.0285x over previous
//
#include <hip/hip_runtime.h>
#include <math.h>

// Problem constants (reference: B=4, N=8192, points are [B,N,3] fp32)
#define BATCH 4
#define NPTS 8192
#define BN (BATCH * NPTS)
#define NZB 16                 // 4 searches x 4 batches
#define QK 8                   // queries per lane in the scan
#define QBLK (256 * QK)        // 2048 queries per scan block
#define SUBT 64                // provenance subtile (rescan covers this many)

// Workspace: [0] double acc | [64] int idx_all[NZB*NPTS] (512KB)
//            [64+512K] float part_d[SPL][NZB*NPTS]
//            [after]   u8    part_t[SPL][NZB*NPTS]   (global subtile id, <128)
// After nn_merge, plane 0 of part_d/part_t holds the merged (best_d, best_g).

__device__ __forceinline__ void pick_ab(int z, const float* pw, const float* pp,
                                        const float* tw, const float* tp,
                                        const float** qa, const float** cb) {
  if (z == 0)      { *qa = pw; *cb = pp; }
  else if (z == 1) { *qa = pp; *cb = pw; }
  else if (z == 2) { *qa = tw; *cb = tp; }
  else             { *qa = tp; *cb = tw; }
}

// ---------------------------------------------------------------------------
// Pass 1: min-distance scan + subtile provenance (unchanged from R3 — VALU
// saturated at ~3 cyc/instr, near the measured 103 TF practical ceiling).
// ---------------------------------------------------------------------------
template <int SPL>
__global__ __launch_bounds__(256, 4) void nn_partial_kernel(
    const float* __restrict__ pw, const float* __restrict__ pp,
    const float* __restrict__ tw, const float* __restrict__ tp,
    float* __restrict__ part_d, unsigned char* __restrict__ part_t) {
  constexpr int SLICE = NPTS / SPL;
  constexpr int NSUB = SLICE / SUBT;
  __shared__ float4 sh[SLICE];

  const int zb = blockIdx.z;
  const int z = zb >> 2;
  const int b = zb & 3;
  const float* qa;
  const float* cb;
  pick_ab(z, pw, pp, tw, tp, &qa, &cb);

  const int tid = threadIdx.x;
  const int cslice = blockIdx.y * SLICE;
  const float* cbb = cb + (size_t)b * NPTS * 3;

  // Stage slice as (x,y,z,||b||^2); b2 formula must match nn_rescan exactly.
  for (int m = tid; m < SLICE; m += 256) {
    const float* c = cbb + (size_t)(cslice + m) * 3;
    const float bx = c[0], by = c[1], bz = c[2];
    sh[m] = make_float4(bx, by, bz, fmaf(bx, bx, fmaf(by, by, bz * bz)));
  }
  __syncthreads();

  const int qbase = blockIdx.x * QBLK;
  float qx[QK], qy[QK], qz[QK], dmin[QK];
  int tile[QK];
  #pragma unroll
  for (int k = 0; k < QK; ++k) {
    const int n = qbase + tid + k * 256;
    const float* q = qa + ((size_t)b * NPTS + n) * 3;
    qx[k] = -2.0f * q[0];
    qy[k] = -2.0f * q[1];
    qz[k] = -2.0f * q[2];
    dmin[k] = INFINITY;
    tile[k] = 0;
  }

  for (int sub = 0; sub < NSUB; ++sub) {
    float pre[QK];
    #pragma unroll
    for (int k = 0; k < QK; ++k) pre[k] = dmin[k];

    const int cb0 = sub * SUBT;
    #pragma unroll 2
    for (int p = 0; p < SUBT / 2; ++p) {
      const float4 c0 = sh[cb0 + 2 * p];
      const float4 c1 = sh[cb0 + 2 * p + 1];
      float t0[QK], t1[QK];
      #pragma unroll
      for (int k = 0; k < QK; ++k)
        t0[k] = fmaf(qx[k], c0.x, fmaf(qy[k], c0.y, fmaf(qz[k], c0.z, c0.w)));
      #pragma unroll
      for (int k = 0; k < QK; ++k)
        t1[k] = fmaf(qx[k], c1.x, fmaf(qy[k], c1.y, fmaf(qz[k], c1.z, c1.w)));
      #pragma unroll
      for (int k = 0; k < QK; ++k)
        dmin[k] = fminf(fminf(t0[k], t1[k]), dmin[k]);   // v_min3_f32
    }
    const int g = blockIdx.y * NSUB + sub;   // global subtile id, [0,128)
    #pragma unroll
    for (int k = 0; k < QK; ++k)
      tile[k] = (dmin[k] < pre[k]) ? g : tile[k];  // strict <: first-min kept
  }

  #pragma unroll
  for (int k = 0; k < QK; ++k) {
    const int n = qbase + tid + k * 256;
    const size_t o = (size_t)blockIdx.y * (NZB * NPTS) + (size_t)zb * NPTS + n;
    part_d[o] = dmin[k];
    part_t[o] = (unsigned char)tile[k];
  }
}

// ---------------------------------------------------------------------------
// Pass 2a: merge splits, THREAD per query. For fixed split s, consecutive
// threads read consecutive addresses -> every load fully coalesced.
// Lexicographic (d, subtile-id) min across splits in ascending order ==
// jnp.argmin first-min (subtile ids follow global candidate order).
// Writes the merged result into plane 0 (each thread only its own slot,
// strictly after reading it).
// ---------------------------------------------------------------------------
template <int SPL>
__global__ __launch_bounds__(256) void nn_merge_kernel(
    float* __restrict__ part_d, unsigned char* __restrict__ part_t,
    double* __restrict__ acc) {
  if (blockIdx.x == 0 && threadIdx.x == 0) *acc = 0.0;  // before loss dispatch

  const int qid = blockIdx.x * 256 + threadIdx.x;  // [0, NZB*NPTS)
  float best_d = part_d[qid];
  int best_g = part_t[qid];
  #pragma unroll
  for (int s = 1; s < SPL; ++s) {
    const float d = part_d[(size_t)s * (NZB * NPTS) + qid];
    const int g = part_t[(size_t)s * (NZB * NPTS) + qid];
    if (d < best_d || (d == best_d && g < best_g)) { best_d = d; best_g = g; }
  }
  part_d[qid] = best_d;
  part_t[qid] = (unsigned char)best_g;
}

// ---------------------------------------------------------------------------
// Pass 2b: rescan, WAVE per query. 64 lanes check the 64 candidates of the
// winning subtile (contiguous 768B, bit-identical fma chain); int-min-reduce
// the first exact match. block = 1024 (16 waves), grid = NZB*NPTS/16.
// ---------------------------------------------------------------------------
__global__ __launch_bounds__(1024) void nn_rescan_kernel(
    const float* __restrict__ pw, const float* __restrict__ pp,
    const float* __restrict__ tw, const float* __restrict__ tp,
    const float* __restrict__ part_d, const unsigned char* __restrict__ part_t,
    int* __restrict__ idx_all) {
  const int qid = (blockIdx.x * 1024 + threadIdx.x) >> 6;  // [0, NZB*NPTS)
  const int lane = threadIdx.x & 63;
  const int zb = qid >> 13;
  const int n = qid & (NPTS - 1);
  const int z = zb >> 2;
  const int b = zb & 3;
  const float* qa;
  const float* cb;
  pick_ab(z, pw, pp, tw, tp, &qa, &cb);

  const float best_d = part_d[qid];            // wave-uniform: broadcast
  const int best_g = part_t[qid];

  const float* q = qa + ((size_t)b * NPTS + n) * 3;
  const float qx = -2.0f * q[0];
  const float qy = -2.0f * q[1];
  const float qz = -2.0f * q[2];
  const float* cbb = cb + (size_t)b * NPTS * 3;

  const int m = best_g * SUBT + lane;          // one candidate per lane
  const float* c = cbb + (size_t)m * 3;
  const float bx = c[0], by = c[1], bz = c[2];
  const float b2 = fmaf(bx, bx, fmaf(by, by, bz * bz));
  const float dd = fmaf(qx, bx, fmaf(qy, by, fmaf(qz, bz, b2)));
  int idx = (dd == best_d) ? m : 0x7fffffff;
  #pragma unroll
  for (int off = 32; off > 0; off >>= 1)
    idx = min(idx, __shfl_down(idx, off));
  if (lane == 0) idx_all[qid] = idx;
}

// ---------------------------------------------------------------------------
// Loss: 4 MSN terms split across blockIdx.y.
// loss = 0.25 * (sum of 4 squared-norm sums) / (B*N)
// ---------------------------------------------------------------------------
__device__ __forceinline__ float3 ld3(const float* __restrict__ p, int i) {
  const float* q = p + (size_t)i * 3;
  return make_float3(q[0], q[1], q[2]);
}

__device__ __forceinline__ float diff_nrm2(float3 a1, float3 a2, float3 b1, float3 b2) {
  const float x = (a1.x - a2.x) - (b1.x - b2.x);
  const float y = (a1.y - a2.y) - (b1.y - b2.y);
  const float z = (a1.z - a2.z) - (b1.z - b2.z);
  return fmaf(x, x, fmaf(y, y, z * z));
}

__global__ __launch_bounds__(256) void loss_kernel(
    const float* __restrict__ pw, const float* __restrict__ pp,
    const float* __restrict__ tw, const float* __restrict__ tp,
    const int* __restrict__ ipw, const int* __restrict__ itw,
    const int* __restrict__ ipp, const int* __restrict__ itp,
    const int* __restrict__ idx_all, double* __restrict__ acc) {
  const int gid = blockIdx.x * 256 + threadIdx.x;  // [0, B*N)
  const int term = blockIdx.y;
  const int b = gid >> 13;
  const int n = gid & (NPTS - 1);
  const int base = b * NPTS;

  const float* PW = pw + (size_t)base * 3;
  const float* PP = pp + (size_t)base * 3;
  const float* TW = tw + (size_t)base * 3;
  const float* TP = tp + (size_t)base * 3;
  const int* I1P = idx_all + (0 * BATCH + b) * NPTS;  // NN pial for white (pred)
  const int* I2P = idx_all + (1 * BATCH + b) * NPTS;  // NN white for pial (pred)
  const int* I1T = idx_all + (2 * BATCH + b) * NPTS;  // NN pial for white (true)
  const int* I2T = idx_all + (3 * BATCH + b) * NPTS;  // NN white for pial (true)

  float sv;
  if (term == 0) {        // msn(yp_inner, yt_inner[i_pred_white])
    const int j = ipw[base + n];
    sv = diff_nrm2(ld3(PP, I1P[n]), ld3(PW, n), ld3(TP, I1T[j]), ld3(TW, j));
  } else if (term == 1) { // msn(yp_inner[i_true_white], yt_inner)
    const int k = itw[base + n];
    sv = diff_nrm2(ld3(PP, I1P[k]), ld3(PW, k), ld3(TP, I1T[n]), ld3(TW, n));
  } else if (term == 2) { // msn(yp_outer, yt_outer[i_pred_pial])
    const int j = ipp[base + n];
    sv = diff_nrm2(ld3(PP, n), ld3(PW, I2P[n]), ld3(TP, j), ld3(TW, I2T[j]));
  } else {                // msn(yp_outer[i_true_pial], yt_outer)
    const int k = itp[base + n];
    sv = diff_nrm2(ld3(PP, k), ld3(PW, I2P[k]), ld3(TP, n), ld3(TW, I2T[n]));
  }

  double ds = (double)sv;
  #pragma unroll
  for (int o = 32; o > 0; o >>= 1) ds += __shfl_down(ds, o, 64);
  if ((threadIdx.x & 63) == 0) atomicAdd(acc, ds);
}

__global__ void finalize_kernel(const double* __restrict__ acc,
                                float* __restrict__ out) {
  out[0] = (float)(0.25 * (*acc) / (double)BN);
}

// ---------------------------------------------------------------------------
template <int SPL>
static void run_pipeline(const float* pw, const float* pp, const float* tw,
                         const float* tp, const int* ipw, const int* itw,
                         const int* ipp, const int* itp, char* ws, float* out,
                         hipStream_t stream) {
  double* acc = (double*)ws;
  int* idx_all = (int*)(ws + 64);
  float* part_d = (float*)(ws + 64 + (size_t)NZB * NPTS * 4);
  unsigned char* part_t =
      (unsigned char*)(ws + 64 + (size_t)NZB * NPTS * 4 +
                       (size_t)SPL * NZB * NPTS * 4);

  dim3 grid_nn(NPTS / QBLK, SPL, NZB);
  nn_partial_kernel<SPL><<<grid_nn, 256, 0, stream>>>(pw, pp, tw, tp, part_d,
                                                      part_t);
  nn_merge_kernel<SPL><<<(NZB * NPTS) / 256, 256, 0, stream>>>(part_d, part_t,
                                                               acc);
  nn_rescan_kernel<<<(NZB * NPTS) / 16, 1024, 0, stream>>>(
      pw, pp, tw, tp, part_d, part_t, idx_all);

  dim3 grid_loss(BN / 256, 4);
  loss_kernel<<<grid_loss, 256, 0, stream>>>(pw, pp, tw, tp, ipw, itw, ipp, itp,
                                             idx_all, acc);
  finalize_kernel<<<1, 1, 0, stream>>>(acc, out);
}

extern "C" void kernel_launch(void* const* d_in, const int* in_sizes, int n_in,
                              void* d_out, int out_size, void* d_ws, size_t ws_size,
                              hipStream_t stream) {
  const float* pw = (const float*)d_in[0];
  const float* pp = (const float*)d_in[1];
  const float* tw = (const float*)d_in[2];
  const float* tp = (const float*)d_in[3];
  const int* ipw = (const int*)d_in[4];
  const int* itw = (const int*)d_in[5];
  const int* ipp = (const int*)d_in[6];
  const int* itp = (const int*)d_in[7];
  char* ws = (char*)d_ws;
  float* out = (float*)d_out;

  // ws need per SPL: 64 + idx(512K) + part_d(SPL*512K) + part_t(SPL*128K)
  const size_t base_need = 64 + (size_t)NZB * NPTS * 4;
  const size_t per_spl = (size_t)NZB * NPTS * 5;
  if (ws_size >= base_need + 32 * per_spl) {
    run_pipeline<32>(pw, pp, tw, tp, ipw, itw, ipp, itp, ws, out, stream);
  } else if (ws_size >= base_need + 16 * per_spl) {
    run_pipeline<16>(pw, pp, tw, tp, ipw, itw, ipp, itp, ws, out, stream);
  } else {
    run_pipeline<8>(pw, pp, tw, tp, ipw, itw, ipp, itp, ws, out, stream);
  }
}